// Round 9
// baseline (317.167 us; speedup 1.0000x reference)
//
#include <hip/hip_runtime.h>
#include <math.h>

#define NB 4096
#define HL 50
#define D  64
#define WPB 4   // waves per block; one batch row per wave

// lane = history entry (0..49 valid), wave = batch row.
// All weights are wave-uniform -> compiler scalarizes to s_load; the hot
// loops are pure v_fmac_f32 (SGPR weight x VGPR activation), no LDS reads.
__global__ __launch_bounds__(256, 2) void uvagg(
    const int* __restrict__ nodes,
    const int* __restrict__ history_uv,
    const int* __restrict__ history_r,
    const int* __restrict__ lengths,
    const float* __restrict__ u2e,
    const float* __restrict__ v2e,
    const float* __restrict__ r2e,
    const float* __restrict__ w1,
    const float* __restrict__ b1,
    const float* __restrict__ w2,
    const float* __restrict__ b2,
    const float* __restrict__ a1,
    const float* __restrict__ ba1,
    const float* __restrict__ a2,
    const float* __restrict__ ba2,
    const float* __restrict__ a3,
    const float* __restrict__ ba3,
    float* __restrict__ out)
{
    const int wv   = threadIdx.x >> 6;
    const int lane = threadIdx.x & 63;
    const int b    = blockIdx.x * WPB + wv;

    __shared__ float c1_s[WPB][D];
    __shared__ float tr_s[WPB][64 * 17];   // padded transpose tile (17-float row stride)

    const int node = nodes[b];     // uniform
    const int len  = lengths[b];   // uniform

    // self embedding: lane d holds uv[d]
    const float uvl = u2e[node * D + lane];

    // ---- c1[j] = ba1[j] + sum_k uv[k]*a1[(64+k)*64+j]  (uniform per b, lane=j) ----
    {
        float c1 = ba1[lane];
        #pragma unroll 16
        for (int k = 0; k < D; ++k) {
            float uk = __shfl(uvl, k, 64);
            c1 = fmaf(uk, a1[(D + k) * D + lane], c1);
        }
        c1_s[wv][lane] = c1;   // same-wave write->read, compiler orders lgkmcnt
    }

    // ---- gather history indices (lane = entry) ----
    const bool e_ok = (lane < HL);
    const int  hidx = b * HL + (e_ok ? lane : 0);
    const int  iuv  = e_ok ? history_uv[hidx] : 0;
    const int  ir   = e_ok ? history_r[hidx]  : 0;
    const float4* euv4 = reinterpret_cast<const float4*>(v2e + (size_t)iuv * D);
    const float4* er4  = reinterpret_cast<const float4*>(r2e + ir * D);

    // ---- stage 1 fused: x = relu([euv,er]@w1+b1); o = relu(x@w2+b2) ----
    float oacc[D];
    #pragma unroll
    for (int j = 0; j < D; ++j) oacc[j] = b2[j];

    #pragma unroll 1
    for (int jc = 0; jc < 4; ++jc) {           // 16-wide x-chunks
        float xc[16];
        #pragma unroll
        for (int jj = 0; jj < 16; ++jj) xc[jj] = b1[jc * 16 + jj];
        #pragma unroll 1
        for (int kc = 0; kc < 8; ++kc) {       // stream inputs 16 at a time
            const float4* src = (kc < 4) ? euv4 : er4;
            const int cb = (kc & 3) * 4;
            float4 v0 = src[cb + 0];
            float4 v1 = src[cb + 1];
            float4 v2 = src[cb + 2];
            float4 v3 = src[cb + 3];
            float in[16] = {v0.x, v0.y, v0.z, v0.w, v1.x, v1.y, v1.z, v1.w,
                            v2.x, v2.y, v2.z, v2.w, v3.x, v3.y, v3.z, v3.w};
            const float* wbase = w1 + (kc * 16) * D + jc * 16;
            #pragma unroll
            for (int kk = 0; kk < 16; ++kk) {
                #pragma unroll
                for (int jj = 0; jj < 16; ++jj)
                    xc[jj] = fmaf(in[kk], wbase[kk * D + jj], xc[jj]);
            }
        }
        #pragma unroll
        for (int jj = 0; jj < 16; ++jj) xc[jj] = fmaxf(xc[jj], 0.f);
        // o += xc-chunk @ w2 rows
        const float* w2base = w2 + (jc * 16) * D;
        #pragma unroll
        for (int jj = 0; jj < 16; ++jj) {
            #pragma unroll
            for (int j = 0; j < D; ++j)
                oacc[j] = fmaf(xc[jj], w2base[jj * D + j], oacc[j]);
        }
    }
    #pragma unroll
    for (int j = 0; j < D; ++j) oacc[j] = fmaxf(oacc[j], 0.f);

    // ---- stage 2 fused: h1 = relu(o@a1[:64]+c1); h2 = relu(h1@a2+ba2) ----
    float h2[D];
    #pragma unroll
    for (int j = 0; j < D; ++j) h2[j] = ba2[j];

    #pragma unroll 1
    for (int jc = 0; jc < 4; ++jc) {
        float hc[16];
        #pragma unroll
        for (int jj = 0; jj < 16; ++jj) hc[jj] = c1_s[wv][jc * 16 + jj];
        const float* wbase = a1 + jc * 16;
        #pragma unroll
        for (int k = 0; k < D; ++k) {
            #pragma unroll
            for (int jj = 0; jj < 16; ++jj)
                hc[jj] = fmaf(oacc[k], wbase[k * D + jj], hc[jj]);
        }
        #pragma unroll
        for (int jj = 0; jj < 16; ++jj) hc[jj] = fmaxf(hc[jj], 0.f);
        const float* w2base = a2 + (jc * 16) * D;
        #pragma unroll
        for (int jj = 0; jj < 16; ++jj) {
            #pragma unroll
            for (int j = 0; j < D; ++j)
                h2[j] = fmaf(hc[jj], w2base[jj * D + j], h2[j]);
        }
    }
    float score = ba3[0];
    #pragma unroll
    for (int j = 0; j < D; ++j) score = fmaf(fmaxf(h2[j], 0.f), a3[j], score);

    // ---- masked softmax over lanes (entries) ----
    const bool valid = (lane < len);   // len <= 50, so lanes >= 50 auto-invalid
    float s = valid ? score : -1e9f;
    float m = s;
    #pragma unroll
    for (int off = 32; off >= 1; off >>= 1) m = fmaxf(m, __shfl_xor(m, off, 64));
    float e = valid ? expf(s - m) : 0.f;
    float sum = e;
    #pragma unroll
    for (int off = 32; off >= 1; off >>= 1) sum += __shfl_xor(sum, off, 64);
    const float att = e / sum;

    // ---- agg[d] = sum_l att_l * o_l[d] via padded-LDS transpose ----
    float* tr = tr_s[wv];
    float aggv = 0.f;
    const int p  = lane >> 4;
    const int dd = lane & 15;
    #pragma unroll
    for (int c = 0; c < 4; ++c) {
        #pragma unroll
        for (int jj = 0; jj < 16; ++jj)
            tr[lane * 17 + jj] = att * oacc[c * 16 + jj];
        float part = 0.f;
        #pragma unroll
        for (int ll = 0; ll < 16; ++ll)
            part += tr[(p * 16 + ll) * 17 + dd];
        part += __shfl_xor(part, 16, 64);
        part += __shfl_xor(part, 32, 64);
        if (c == (lane >> 4)) aggv = part;
    }

    out[b * D + lane] = (len > 0) ? aggv : uvl;
}

extern "C" void kernel_launch(void* const* d_in, const int* in_sizes, int n_in,
                              void* d_out, int out_size, void* d_ws, size_t ws_size,
                              hipStream_t stream) {
    const int*   nodes = (const int*)d_in[0];
    const int*   huv   = (const int*)d_in[1];
    const int*   hr    = (const int*)d_in[2];
    const int*   lens  = (const int*)d_in[3];
    const float* u2e   = (const float*)d_in[4];
    const float* v2e   = (const float*)d_in[5];
    const float* r2e   = (const float*)d_in[6];
    const float* w1    = (const float*)d_in[7];
    const float* b1    = (const float*)d_in[8];
    const float* w2    = (const float*)d_in[9];
    const float* b2    = (const float*)d_in[10];
    const float* a1    = (const float*)d_in[11];
    const float* ba1   = (const float*)d_in[12];
    const float* a2    = (const float*)d_in[13];
    const float* ba2   = (const float*)d_in[14];
    const float* a3    = (const float*)d_in[15];
    const float* ba3   = (const float*)d_in[16];
    float* outp = (float*)d_out;

    uvagg<<<NB / WPB, 256, 0, stream>>>(nodes, huv, hr, lens, u2e, v2e, r2e,
                                        w1, b1, w2, b2, a1, ba1, a2, ba2, a3, ba3,
                                        outp);
}

// Round 10
// 151.053 us; speedup vs baseline: 2.0997x; 2.0997x over previous
//
#include <hip/hip_runtime.h>
#include <math.h>

#define NB 4096
#define HL 50
#define WPB 4   // waves per block; one batch row per wave

typedef __attribute__((ext_vector_type(8))) short short8;   // 8 bf16 (4 VGPRs)
typedef __attribute__((ext_vector_type(4))) float f32x4;    // MFMA acc

union frag_u { uint4 q; short8 s; };

// round-to-nearest-even f32->bf16, pack two into u32 (a=low half, b=high half)
__device__ __forceinline__ unsigned pk2(float a, float b) {
    union { float f; unsigned u; } x, y;
    x.f = a; y.f = b;
    unsigned lo = (x.u + 0x7FFFu + ((x.u >> 16) & 1u)) >> 16;
    unsigned hi = (y.u + 0x7FFFu + ((y.u >> 16) & 1u)) & 0xFFFF0000u;
    return lo | hi;
}

__device__ __forceinline__ f32x4 relu4(f32x4 v) {
    f32x4 r;
    r[0] = fmaxf(v[0], 0.f); r[1] = fmaxf(v[1], 0.f);
    r[2] = fmaxf(v[2], 0.f); r[3] = fmaxf(v[3], 0.f);
    return r;
}

// wave = one batch row. MFMA: channels = M (rows), entries = N (cols).
// A-operands (weights^T) packed once/block into LDS in fragment order.
// The k-slot permutation is applied IDENTICALLY on A-pack and B-stage sides,
// so any HW k-ordering cancels (sum over k is permutation-invariant).
__global__ __launch_bounds__(256, 2) void uvagg(
    const int* __restrict__ nodes,
    const int* __restrict__ history_uv,
    const int* __restrict__ history_r,
    const int* __restrict__ lengths,
    const float* __restrict__ u2e,
    const float* __restrict__ v2e,
    const float* __restrict__ r2e,
    const float* __restrict__ w1,
    const float* __restrict__ b1,
    const float* __restrict__ w2,
    const float* __restrict__ b2,
    const float* __restrict__ a1,
    const float* __restrict__ ba1,
    const float* __restrict__ a2,
    const float* __restrict__ ba2,
    const float* __restrict__ a3,
    const float* __restrict__ ba3,
    float* __restrict__ out)
{
    const int wv   = threadIdx.x >> 6;
    const int lane = threadIdx.x & 63;
    const int g    = lane >> 4;      // k-group / row-group
    const int c16  = lane & 15;      // col-within-tile
    const int b    = blockIdx.x * WPB + wv;

    // LDS: packed weight A-tiles (40 x 1KB), c1 vector, per-wave stage buffer
    __shared__ uint4 s_wpack[40 * 64];                 // 40 KB
    __shared__ __align__(16) float s_c1[WPB][64];      // 1 KB
    __shared__ uint4 s_stage[WPB][256];                // 16 KB (B-stage / transitions)

    // ---- cooperative weight packing: tiles 0-15 w1^T, 16-23 w2^T, 24-31 a1^T(k<64), 32-39 a2^T ----
    {
        const int tid = threadIdx.x;
        #pragma unroll 1
        for (int t = tid; t < 2560; t += 256) {
            const int tile = t >> 6, ln = t & 63;
            const float* src; int kb, mt;
            if (tile < 16)      { src = w1; kb = (tile & 3) * 32; mt = tile >> 2; }
            else if (tile < 24) { src = w2; kb = (tile & 1) * 32; mt = (tile - 16) >> 1; }
            else if (tile < 32) { src = a1; kb = (tile & 1) * 32; mt = (tile - 24) >> 1; }
            else                { src = a2; kb = (tile & 1) * 32; mt = (tile - 32) >> 1; }
            const float* p = src + (size_t)(kb + (ln >> 4) * 8) * 64 + mt * 16 + (ln & 15);
            uint4 o;
            o.x = pk2(p[0 * 64], p[1 * 64]);
            o.y = pk2(p[2 * 64], p[3 * 64]);
            o.z = pk2(p[4 * 64], p[5 * 64]);
            o.w = pk2(p[6 * 64], p[7 * 64]);
            s_wpack[tile * 64 + ln] = o;
        }
    }

    const int node = nodes[b];     // uniform
    const int len  = lengths[b];   // uniform
    const float uvl = u2e[node * 64 + lane];

    // ---- c1[j] = ba1[j] + sum_k uv[k]*a1[(64+k)*64+j]  (lane = j) ----
    {
        float c1 = ba1[lane];
        #pragma unroll 16
        for (int k = 0; k < 64; ++k)
            c1 = fmaf(__shfl(uvl, k, 64), a1[(64 + k) * 64 + lane], c1);
        s_c1[wv][lane] = c1;
    }
    __syncthreads();   // weights packed + c1 ready

    // ---- gather pointers (lane = entry) ----
    const bool e_ok = (lane < HL);
    const int  hidx = b * HL + (e_ok ? lane : 0);
    const float4* euv4 = (const float4*)(v2e + (size_t)history_uv[hidx] * 64);
    const float4* er4  = (const float4*)(r2e + (size_t)history_r[hidx] * 64);

    uint4* stw = &s_stage[wv][0];
    uint2* t2  = (uint2*)stw;

    // transition write index per mt (C pair {c0,c0+1},{c0+2,c0+3} -> B' slots)
    int twi[4];
    #pragma unroll
    for (int mt = 0; mt < 4; ++mt) {
        const int gq = (mt & 1) * 2 + (g >> 1);
        twi[mt] = (mt >> 1) * 128 + (c16 + 16 * gq) * 2 + (g & 1);
    }

    // ================= layer 1: x^T = w1^T @ in^T =================
    f32x4 accx[4][4];
    #pragma unroll
    for (int mt = 0; mt < 4; ++mt)
        #pragma unroll
        for (int nt = 0; nt < 4; ++nt)
            accx[mt][nt] = (f32x4){0.f, 0.f, 0.f, 0.f};

    #pragma unroll
    for (int kt = 0; kt < 4; ++kt) {
        const float4* s4 = (kt < 2) ? euv4 : er4;
        const int rb = (kt & 1) * 8;
        #pragma unroll
        for (int gg = 0; gg < 4; ++gg) {                 // stage entry row chunk k=kt*32+gg*8..+7
            float4 va = s4[rb + gg * 2];
            float4 vb = s4[rb + gg * 2 + 1];
            uint4 o;
            o.x = pk2(va.x, va.y); o.y = pk2(va.z, va.w);
            o.z = pk2(vb.x, vb.y); o.w = pk2(vb.z, vb.w);
            stw[g * 64 + c16 + 16 * gg] = o;             // tile nt=g(=entry>>4)
        }
        frag_u Bf[4];
        #pragma unroll
        for (int nt = 0; nt < 4; ++nt) Bf[nt].q = stw[nt * 64 + lane];
        #pragma unroll
        for (int mt = 0; mt < 4; ++mt) {
            frag_u Af; Af.q = s_wpack[(mt * 4 + kt) * 64 + lane];
            #pragma unroll
            for (int nt = 0; nt < 4; ++nt)
                accx[mt][nt] = __builtin_amdgcn_mfma_f32_16x16x32_bf16(
                    Af.s, Bf[nt].s, accx[mt][nt], 0, 0, 0);
        }
    }

    // x = relu(x + b1) -> bf16 pairs
    unsigned xp[4][4][2];
    #pragma unroll
    for (int mt = 0; mt < 4; ++mt) {
        const f32x4 b1q = *(const f32x4*)(b1 + mt * 16 + g * 4);
        #pragma unroll
        for (int nt = 0; nt < 4; ++nt) {
            f32x4 a = relu4(accx[mt][nt] + b1q);
            xp[mt][nt][0] = pk2(a[0], a[1]);
            xp[mt][nt][1] = pk2(a[2], a[3]);
        }
    }

    f32x4 of[4][4];        // o kept in f32 for final aggregation
    float myscore = 0.f;

    // ================= layers 2-4, per entry-column tile nt =================
    #pragma unroll
    for (int nt = 0; nt < 4; ++nt) {
        // ---- x -> B' ----
        #pragma unroll
        for (int mt = 0; mt < 4; ++mt)
            t2[twi[mt]] = make_uint2(xp[mt][nt][0], xp[mt][nt][1]);
        frag_u Bp0, Bp1;
        Bp0.q = stw[lane]; Bp1.q = stw[64 + lane];

        // ---- layer 2: o = relu(w2^T @ x + b2) ----
        f32x4 acco[4];
        #pragma unroll
        for (int mt = 0; mt < 4; ++mt) acco[mt] = (f32x4){0.f, 0.f, 0.f, 0.f};
        #pragma unroll
        for (int kt2 = 0; kt2 < 2; ++kt2) {
            #pragma unroll
            for (int mt = 0; mt < 4; ++mt) {
                frag_u A; A.q = s_wpack[(16 + mt * 2 + kt2) * 64 + lane];
                acco[mt] = __builtin_amdgcn_mfma_f32_16x16x32_bf16(
                    A.s, (kt2 ? Bp1 : Bp0).s, acco[mt], 0, 0, 0);
            }
        }
        unsigned op0[4], op1[4];
        #pragma unroll
        for (int mt = 0; mt < 4; ++mt) {
            const f32x4 b2q = *(const f32x4*)(b2 + mt * 16 + g * 4);
            f32x4 o = relu4(acco[mt] + b2q);
            of[mt][nt] = o;
            op0[mt] = pk2(o[0], o[1]); op1[mt] = pk2(o[2], o[3]);
        }

        // ---- o -> B'' ; layer 3: h1 = relu(a1^T @ o + c1) ----
        #pragma unroll
        for (int mt = 0; mt < 4; ++mt) t2[twi[mt]] = make_uint2(op0[mt], op1[mt]);
        Bp0.q = stw[lane]; Bp1.q = stw[64 + lane];
        f32x4 acch[4];
        #pragma unroll
        for (int mt = 0; mt < 4; ++mt) acch[mt] = (f32x4){0.f, 0.f, 0.f, 0.f};
        #pragma unroll
        for (int kt2 = 0; kt2 < 2; ++kt2) {
            #pragma unroll
            for (int mt = 0; mt < 4; ++mt) {
                frag_u A; A.q = s_wpack[(24 + mt * 2 + kt2) * 64 + lane];
                acch[mt] = __builtin_amdgcn_mfma_f32_16x16x32_bf16(
                    A.s, (kt2 ? Bp1 : Bp0).s, acch[mt], 0, 0, 0);
            }
        }
        unsigned hp0[4], hp1[4];
        #pragma unroll
        for (int mt = 0; mt < 4; ++mt) {
            const f32x4 c1q = *(const f32x4*)&s_c1[wv][mt * 16 + g * 4];
            f32x4 h = relu4(acch[mt] + c1q);
            hp0[mt] = pk2(h[0], h[1]); hp1[mt] = pk2(h[2], h[3]);
        }

        // ---- h1 -> B''' ; layer 4: h2 = relu(a2^T @ h1 + ba2); score = h2 . a3 ----
        #pragma unroll
        for (int mt = 0; mt < 4; ++mt) t2[twi[mt]] = make_uint2(hp0[mt], hp1[mt]);
        Bp0.q = stw[lane]; Bp1.q = stw[64 + lane];
        f32x4 acc2[4];
        #pragma unroll
        for (int mt = 0; mt < 4; ++mt) acc2[mt] = (f32x4){0.f, 0.f, 0.f, 0.f};
        #pragma unroll
        for (int kt2 = 0; kt2 < 2; ++kt2) {
            #pragma unroll
            for (int mt = 0; mt < 4; ++mt) {
                frag_u A; A.q = s_wpack[(32 + mt * 2 + kt2) * 64 + lane];
                acc2[mt] = __builtin_amdgcn_mfma_f32_16x16x32_bf16(
                    A.s, (kt2 ? Bp1 : Bp0).s, acc2[mt], 0, 0, 0);
            }
        }
        float s = 0.f;
        #pragma unroll
        for (int mt = 0; mt < 4; ++mt) {
            const f32x4 ba2q = *(const f32x4*)(ba2 + mt * 16 + g * 4);
            const f32x4 a3q  = *(const f32x4*)(a3  + mt * 16 + g * 4);
            #pragma unroll
            for (int r = 0; r < 4; ++r)
                s = fmaf(fmaxf(acc2[mt][r] + ba2q[r], 0.f), a3q[r], s);
        }
        s += __shfl_xor(s, 16, 64);
        s += __shfl_xor(s, 32, 64);      // score for entry nt*16+c16, replicated
        if (g == nt) myscore = s;        // lane l ends with score[l]
    }

    // ---- masked softmax over entries (lane = entry); ba3 shift-invariant, skipped ----
    const bool valid = (lane < len);
    float sv = valid ? myscore : -1e9f;
    float m = sv;
    #pragma unroll
    for (int off = 32; off >= 1; off >>= 1) m = fmaxf(m, __shfl_xor(m, off, 64));
    float e = valid ? expf(sv - m) : 0.f;
    float sum = e;
    #pragma unroll
    for (int off = 32; off >= 1; off >>= 1) sum += __shfl_xor(sum, off, 64);
    const float att = e / sum;

    // ---- agg[d] = sum_l att[l] * o[d][l]  (o in C-layout, f32) ----
    float attn[4];
    #pragma unroll
    for (int nt = 0; nt < 4; ++nt) attn[nt] = __shfl(att, nt * 16 + c16, 64);

    f32x4 agg[4];
    #pragma unroll
    for (int mt = 0; mt < 4; ++mt) {
        f32x4 a = of[mt][0] * attn[0];
        a += of[mt][1] * attn[1];
        a += of[mt][2] * attn[2];
        a += of[mt][3] * attn[3];
        agg[mt] = a;
    }
    #pragma unroll
    for (int off = 1; off <= 8; off <<= 1) {
        #pragma unroll
        for (int mt = 0; mt < 4; ++mt) {
            #pragma unroll
            for (int r = 0; r < 4; ++r)
                agg[mt][r] += __shfl_xor(agg[mt][r], off, 64);
        }
    }

    if (c16 == 0) {   // 4 writer lanes x 4 mt float4 stores cover d=0..63
        #pragma unroll
        for (int mt = 0; mt < 4; ++mt) {
            f32x4 res = agg[mt];
            if (len <= 0)
                res = *(const f32x4*)(u2e + (size_t)node * 64 + mt * 16 + g * 4);
            *(f32x4*)(out + (size_t)b * 64 + mt * 16 + g * 4) = res;
        }
    }
}

extern "C" void kernel_launch(void* const* d_in, const int* in_sizes, int n_in,
                              void* d_out, int out_size, void* d_ws, size_t ws_size,
                              hipStream_t stream) {
    const int*   nodes = (const int*)d_in[0];
    const int*   huv   = (const int*)d_in[1];
    const int*   hr    = (const int*)d_in[2];
    const int*   lens  = (const int*)d_in[3];
    const float* u2e   = (const float*)d_in[4];
    const float* v2e   = (const float*)d_in[5];
    const float* r2e   = (const float*)d_in[6];
    const float* w1    = (const float*)d_in[7];
    const float* b1    = (const float*)d_in[8];
    const float* w2    = (const float*)d_in[9];
    const float* b2    = (const float*)d_in[10];
    const float* a1    = (const float*)d_in[11];
    const float* ba1   = (const float*)d_in[12];
    const float* a2    = (const float*)d_in[13];
    const float* ba2   = (const float*)d_in[14];
    const float* a3    = (const float*)d_in[15];
    const float* ba3   = (const float*)d_in[16];
    float* outp = (float*)d_out;

    uvagg<<<NB / WPB, 256, 0, stream>>>(nodes, huv, hr, lens, u2e, v2e, r2e,
                                        w1, b1, w2, b2, a1, ba1, a2, ba2, a3, ba3,
                                        outp);
}